// Round 13
// baseline (126.548 us; speedup 1.0000x reference)
//
#include <hip/hip_runtime.h>
#include <hip/hip_bf16.h>

#define BB 2
#define SS 2048
#define EE 1024
#define HH 16
#define DD 64
#define MT (BB*SS)     // 4096 tokens
#define NQ (3*EE)      // 3072

typedef unsigned short u16;
typedef __bf16 bf16t;
typedef bf16t bf16x8 __attribute__((ext_vector_type(8)));
typedef short short8v __attribute__((ext_vector_type(8)));
typedef float f32x4 __attribute__((ext_vector_type(4)));

#define AS1 __attribute__((address_space(1)))
#define AS3 __attribute__((address_space(3)))

__device__ __forceinline__ u16 f2b(float f) {
  unsigned u = __builtin_bit_cast(unsigned, f);
  u += 0x7FFF + ((u >> 16) & 1);   // RNE
  return (u16)(u >> 16);
}

__device__ __forceinline__ unsigned cvtpk(float lo, float hi) {
  unsigned r;
  asm("v_cvt_pk_bf16_f32 %0, %1, %2" : "=v"(r) : "v"(lo), "v"(hi));
  return r;
}

__device__ __forceinline__ void gload_lds16(const void* g, void* l) {
  __builtin_amdgcn_global_load_lds((const AS1 void*)(g), (AS3 void*)(l), 16, 0, 0);
}

__device__ __forceinline__ f32x4 mfma_bf16(short8v a, short8v b, f32x4 c) {
  return __builtin_amdgcn_mfma_f32_16x16x32_bf16(
      __builtin_bit_cast(bf16x8, a), __builtin_bit_cast(bf16x8, b), c, 0, 0, 0);
}

// scale folded into Q: 1/sqrt(64) * log2(e)
#define QSCALE 0.18033688f

// ---------------- prologue: cast x -> bf16 ----------------
__global__ void __launch_bounds__(256) cast_kernel(const float* __restrict__ in,
                                                   u16* __restrict__ out, int n) {
  int i = (blockIdx.x * 256 + threadIdx.x) * 4;
  if (i + 3 < n) {
    float4 v = *(const float4*)(in + i);
    ushort4 o;
    o.x = f2b(v.x); o.y = f2b(v.y); o.z = f2b(v.z); o.w = f2b(v.w);
    *(ushort4*)(out + i) = o;
  }
}

// W [K][N] f32 -> WT [N][K] bf16, 64x64 LDS tile (coalesced both sides)
__global__ void __launch_bounds__(256) transpose_kernel(const float* __restrict__ W,
                                                        u16* __restrict__ WT,
                                                        int K, int N) {
  __shared__ float t[64][65];
  int k0 = blockIdx.y * 64, n0 = blockIdx.x * 64;
  int r = threadIdx.x >> 4;          // 0..15
  int c4 = (threadIdx.x & 15) * 4;   // 0..60
#pragma unroll
  for (int i = 0; i < 4; ++i) {
    float4 v = *(const float4*)(W + (size_t)(k0 + r + i * 16) * N + n0 + c4);
    t[r + i * 16][c4 + 0] = v.x; t[r + i * 16][c4 + 1] = v.y;
    t[r + i * 16][c4 + 2] = v.z; t[r + i * 16][c4 + 3] = v.w;
  }
  __syncthreads();
#pragma unroll
  for (int i = 0; i < 4; ++i) {
    ushort4 o;
    o.x = f2b(t[c4 + 0][r + i * 16]); o.y = f2b(t[c4 + 1][r + i * 16]);
    o.z = f2b(t[c4 + 2][r + i * 16]); o.w = f2b(t[c4 + 3][r + i * 16]);
    *(ushort4*)(WT + (size_t)(n0 + r + i * 16) * K + k0 + c4) = o;
  }
}

// ---------------- QKV GEMM (2-phase dbuf): C = x @ Wqkv + b -> Q,K,Vt ------
__global__ void __launch_bounds__(256) gemm_qkv_kernel(
    const u16* __restrict__ A, const u16* __restrict__ BT,
    const float* __restrict__ bias,
    u16* __restrict__ Qs, u16* __restrict__ Ks, u16* __restrict__ Vt) {
  __shared__ u16 As[8192];   // 2 x 128x32
  __shared__ u16 Bs[8192];
  const int K = EE;
  int tid = threadIdx.x;
  int w = tid >> 6, lane = tid & 63;
  int g = lane >> 4, q = lane & 15;
  int m0 = blockIdx.y * 128, n0 = blockIdx.x * 128;
  int wm = (w >> 1) * 64, wn = (w & 1) * 64;

  f32x4 acc[4][4] = {};

  int r = tid >> 2;
  int kc = (tid & 3) * 8;
  const u16* ga = A + (size_t)(m0 + r) * K + kc;
  const u16* gb = BT + (size_t)(n0 + r) * K + kc;
  u16* lA0 = As + w * 512;
  u16* lA1 = As + 2048 + w * 512;
  u16* lB0 = Bs + w * 512;
  u16* lB1 = Bs + 2048 + w * 512;

  // prologue: stage k=0 into buf0
  gload_lds16(ga, lA0);
  gload_lds16(ga + 64 * K, lA1);
  gload_lds16(gb, lB0);
  gload_lds16(gb + 64 * K, lB1);
  ga += 32; gb += 32;
  __syncthreads();

  int cur = 0;
  for (int k0 = 0; k0 < K; k0 += 32) {
    if (k0 + 32 < K) {               // issue next-tile staging BEFORE compute
      int nx = (cur ^ 1) * 4096;
      gload_lds16(ga, lA0 + nx);
      gload_lds16(ga + 64 * K, lA1 + nx);
      gload_lds16(gb, lB0 + nx);
      gload_lds16(gb + 64 * K, lB1 + nx);
      ga += 32; gb += 32;
    }
    const u16* Ab = As + cur * 4096;
    const u16* Bb = Bs + cur * 4096;
    short8v af[4], bfv[4];
#pragma unroll
    for (int m = 0; m < 4; ++m)
      af[m] = *(const short8v*)(Ab + (wm + m * 16 + q) * 32 + g * 8);
#pragma unroll
    for (int n = 0; n < 4; ++n)
      bfv[n] = *(const short8v*)(Bb + (wn + n * 16 + q) * 32 + g * 8);
#pragma unroll
    for (int m = 0; m < 4; ++m)
#pragma unroll
      for (int n = 0; n < 4; ++n)
        acc[m][n] = mfma_bf16(af[m], bfv[n], acc[m][n]);
    __syncthreads();                 // drains staged loads; swap safe
    cur ^= 1;
  }

#pragma unroll
  for (int m = 0; m < 4; ++m) {
    int row0 = m0 + wm + m * 16 + g * 4;
#pragma unroll
    for (int n = 0; n < 4; ++n) {
      int col = n0 + wn + n * 16 + q;
      float bi = bias[col];
      int t = col >> 10;
      int h = (col >> 6) & 15;
      int d = col & 63;
      int b = row0 >> 11, s0 = row0 & 2047;
      size_t bh = (size_t)b * HH + h;
      if (t == 2) {
        ushort4 vv;
        vv.x = f2b(acc[m][n][0] + bi); vv.y = f2b(acc[m][n][1] + bi);
        vv.z = f2b(acc[m][n][2] + bi); vv.w = f2b(acc[m][n][3] + bi);
        *(ushort4*)&Vt[(bh * DD + d) * SS + s0] = vv;
      } else if (t == 0) {
#pragma unroll
        for (int r2 = 0; r2 < 4; ++r2)
          Qs[(bh * SS + s0 + r2) * DD + d] = f2b((acc[m][n][r2] + bi) * QSCALE);
      } else {
#pragma unroll
        for (int r2 = 0; r2 < 4; ++r2)
          Ks[(bh * SS + s0 + r2) * DD + d] = f2b(acc[m][n][r2] + bi);
      }
    }
  }
}

// ---------------- causal flash attention (4-wave LDS-staged, swapped QK^T) --
// Block = 256 threads = 4 waves x 16 q-rows = 64-row chunk c; tiles = c+1.
// 1024 blocks; chunk map c = (t&1)? 8t+7-r : 8t+r (t=i>>3, r=i&7) makes every
// CU's 4 co-resident blocks sum to exactly 66 tile-units. LDS 40KB -> 4
// blocks/CU (= LDS cap 160KB). K/V staged double-buffered via global_load_lds
// (2 calls per matrix per tile), rule-21 XOR-swizzle. Swapped S^T = mfma(K,Q)
// keeps q-rows lane-local; setprio(1) around MFMA clusters (T5: 4 blocks/CU
// give phase diversity); defer-max THR=8.
__global__ void __launch_bounds__(256) attn_kernel(
    const u16* __restrict__ Qg, const u16* __restrict__ Kg,
    const u16* __restrict__ Vg, u16* __restrict__ O) {
  __shared__ char lds[40960];          // K dbuf 2x8K | V dbuf 2x8K @16384 | P 4x2K @32768
  const int tid = threadIdx.x;
  const int w = tid >> 6, lane = tid & 63;
  const int g = lane >> 4, q = lane & 15;
  const int bid = blockIdx.x;          // 0..1023
  const int bh = bid & 31;             // bid%8 -> XCD; K/V L2-resident (4 heads/XCD)
  const int i = bid >> 5;              // 0..31
  const int t8 = i >> 3, r8 = i & 7;
  const int c = (t8 & 1) ? (8 * t8 + 7 - r8) : (8 * t8 + r8);  // chunk 0..31
  const int b = bh >> 4, h = bh & 15;
  char* Pw = lds + 32768 + w * 2048;
  const int qsw = (q & 7) << 4;        // swizzle for this lane's rows (row&7 == q&7)

  const char* Qp = (const char*)Qg + (size_t)bh * (SS * 128);
  const char* Kp = (const char*)Kg + (size_t)bh * (SS * 128);
  const char* Vp = (const char*)Vg + (size_t)bh * (SS * 128);  // [d][s]

  // staging map: call j covers elements e = tid + j*256; e -> (row=e>>3, 16B chunk=e&7)
  // LDS linear offset e*16 = w*1024 + lane*16 + j*4096 (wave-uniform bases)
  const int sr0 = tid >> 3;
  const int sc0 = ((tid & 7) * 16) ^ ((sr0 & 7) << 4);
  const int sr1 = (tid + 256) >> 3;
  const int sc1 = ((tid & 7) * 16) ^ ((sr1 & 7) << 4);
  const char* Ksrc0 = Kp + sr0 * 128 + sc0;
  const char* Ksrc1 = Kp + sr1 * 128 + sc1;
  const char* Vsrc0 = Vp + (size_t)sr0 * (SS * 2) + sc0;
  const char* Vsrc1 = Vp + (size_t)sr1 * (SS * 2) + sc1;
  char* Kd0 = lds + w * 1024;
  char* Kd1 = lds + w * 1024 + 4096;
  char* Vd0 = lds + 16384 + w * 1024;
  char* Vd1 = lds + 16384 + w * 1024 + 4096;

  const int nt = c + 1;
  const int qw = c * 64 + w * 16;      // wave's first q row

  short8v aq0 = *(const short8v*)(Qp + (size_t)(qw + q) * 128 + g * 16);
  short8v aq1 = *(const short8v*)(Qp + (size_t)(qw + q) * 128 + 64 + g * 16);

  f32x4 oacc[4] = {};                  // O^T[d=vfi*16+g*4+r2][qrow=qw+q]
  float mrun = -1e30f, lrun = 0.f;

  // prologue: stage tile 0
  gload_lds16(Ksrc0, Kd0);
  gload_lds16(Ksrc1, Kd1);
  gload_lds16(Vsrc0, Vd0);
  gload_lds16(Vsrc1, Vd1);
  __syncthreads();

  for (int s = 0; s < nt; ++s) {
    const int buf = s & 1;
    if (s + 1 < nt) {                  // issue next-tile staging before compute
      size_t ko = (size_t)(s + 1) * 8192;   // K: 64 rows x 128B
      int vo = (s + 1) * 128;               // V: 64 cols x 2B
      int bo = (buf ^ 1) * 8192;
      gload_lds16(Ksrc0 + ko, Kd0 + bo);
      gload_lds16(Ksrc1 + ko, Kd1 + bo);
      gload_lds16(Vsrc0 + vo, Vd0 + bo);
      gload_lds16(Vsrc1 + vo, Vd1 + bo);
    }
    const int kv0 = s << 6;
    if (kv0 <= qw + 15) {              // wave has unmasked work this tile
      const char* Kc = lds + buf * 8192;
      const char* Vc = lds + 16384 + buf * 8192;
      // ---- K fragments from swizzled LDS ----
      short8v kf[4][2];
#pragma unroll
      for (int cc = 0; cc < 4; ++cc) {
        const char* kb = Kc + (cc * 16 + q) * 128;
        kf[cc][0] = *(const short8v*)(kb + ((g * 16) ^ qsw));
        kf[cc][1] = *(const short8v*)(kb + ((64 + g * 16) ^ qsw));
      }
      // ---- S^T = K Q^T ----
      f32x4 st[4];
      __builtin_amdgcn_s_setprio(1);
#pragma unroll
      for (int cc = 0; cc < 4; ++cc) {
        f32x4 z = {};
        z = mfma_bf16(kf[cc][0], aq0, z);
        z = mfma_bf16(kf[cc][1], aq1, z);
        st[cc] = z;
      }
      __builtin_amdgcn_s_setprio(0);
      // ---- V^T fragments from swizzled LDS ----
      short8v vf[4][2];
#pragma unroll
      for (int v = 0; v < 4; ++v) {
        const char* vb = Vc + (v * 16 + q) * 128;
        vf[v][0] = *(const short8v*)(vb + ((g * 16) ^ qsw));
        vf[v][1] = *(const short8v*)(vb + ((64 + g * 16) ^ qsw));
      }
      // ---- causal mask (diagonal tiles only) ----
      if (kv0 + 63 > qw) {
        int row = qw + q;
#pragma unroll
        for (int cc = 0; cc < 4; ++cc) {
          int kvb = kv0 + cc * 16 + g * 4;
#pragma unroll
          for (int r2 = 0; r2 < 4; ++r2)
            if (kvb + r2 > row) st[cc][r2] = -1e30f;
        }
      }
      // ---- online softmax (base-2; row lane-local, 2 shuffles) + defer-max --
      f32x4 t01, t23;
#pragma unroll
      for (int r2 = 0; r2 < 4; ++r2) {
        t01[r2] = fmaxf(st[0][r2], st[1][r2]);
        t23[r2] = fmaxf(st[2][r2], st[3][r2]);
      }
      float mx = fmaxf(fmaxf(fmaxf(t01[0], t01[1]), fmaxf(t01[2], t01[3])),
                       fmaxf(fmaxf(t23[0], t23[1]), fmaxf(t23[2], t23[3])));
      mx = fmaxf(mx, __shfl_xor(mx, 16));
      mx = fmaxf(mx, __shfl_xor(mx, 32));
      if (!__all(mx - mrun <= 8.f)) {  // T13: rescale only on real growth
        float mnew = fmaxf(mrun, mx);
        float alpha = exp2f(mrun - mnew);
        mrun = mnew;
        lrun *= alpha;
#pragma unroll
        for (int vfi = 0; vfi < 4; ++vfi)
#pragma unroll
          for (int r2 = 0; r2 < 4; ++r2) oacc[vfi][r2] *= alpha;
      }
      f32x4 sum4 = {};
#pragma unroll
      for (int cc = 0; cc < 4; ++cc)
#pragma unroll
        for (int r2 = 0; r2 < 4; ++r2) {
          float pv = exp2f(st[cc][r2] - mrun);
          st[cc][r2] = pv;
          sum4[r2] += pv;
        }
      float sm = (sum4[0] + sum4[1]) + (sum4[2] + sum4[3]);
      sm += __shfl_xor(sm, 16);
      sm += __shfl_xor(sm, 32);
      lrun += sm;
      // ---- P -> per-wave LDS packed bf16x2 (row = q, kv-contig) ----
      char* basep = Pw + q * 128;
#pragma unroll
      for (int cc = 0; cc < 4; ++cc) {
        unsigned p01 = cvtpk(st[cc][0], st[cc][1]);
        unsigned p23 = cvtpk(st[cc][2], st[cc][3]);
        *(unsigned*)(basep + ((32 * cc + 8 * g + 0) ^ qsw)) = p01;
        *(unsigned*)(basep + ((32 * cc + 8 * g + 4) ^ qsw)) = p23;
      }
      short8v pa0 = *(const short8v*)(basep + ((g * 16) ^ qsw));
      short8v pa1 = *(const short8v*)(basep + ((64 + g * 16) ^ qsw));
      // ---- O^T += V^T P ----
      __builtin_amdgcn_s_setprio(1);
#pragma unroll
      for (int vfi = 0; vfi < 4; ++vfi) {
        oacc[vfi] = mfma_bf16(vf[vfi][0], pa0, oacc[vfi]);
        oacc[vfi] = mfma_bf16(vf[vfi][1], pa1, oacc[vfi]);
      }
      __builtin_amdgcn_s_setprio(0);
    }
    __syncthreads();                   // staged loads drained; buffers safe
  }

  // ---- epilogue ----
  {
    float inv = 1.0f / lrun;
    int row = qw + q;
    char* obase = (char*)O + (((size_t)b * SS + row) * EE + h * 64) * 2;
#pragma unroll
    for (int vfi = 0; vfi < 4; ++vfi) {
      uint2 o;
      o.x = cvtpk(oacc[vfi][0] * inv, oacc[vfi][1] * inv);
      o.y = cvtpk(oacc[vfi][2] * inv, oacc[vfi][3] * inv);
      *(uint2*)(obase + (vfi * 16 + g * 4) * 2) = o;
    }
  }
}

// ---------------- output projection GEMM (2-phase dbuf) ---------------------
__global__ void __launch_bounds__(256) gemm_out_kernel(
    const u16* __restrict__ A, const u16* __restrict__ BT,
    const float* __restrict__ bias, float* __restrict__ Cout) {
  __shared__ u16 As[8192];
  __shared__ u16 Bs[8192];
  const int K = EE;
  int tid = threadIdx.x;
  int w = tid >> 6, lane = tid & 63;
  int g = lane >> 4, q = lane & 15;
  int m0 = blockIdx.y * 128, n0 = blockIdx.x * 128;
  int wm = (w >> 1) * 64, wn = (w & 1) * 64;

  f32x4 acc[4][4] = {};

  int r = tid >> 2;
  int kc = (tid & 3) * 8;
  const u16* ga = A + (size_t)(m0 + r) * K + kc;
  const u16* gb = BT + (size_t)(n0 + r) * K + kc;
  u16* lA0 = As + w * 512;
  u16* lA1 = As + 2048 + w * 512;
  u16* lB0 = Bs + w * 512;
  u16* lB1 = Bs + 2048 + w * 512;

  gload_lds16(ga, lA0);
  gload_lds16(ga + 64 * K, lA1);
  gload_lds16(gb, lB0);
  gload_lds16(gb + 64 * K, lB1);
  ga += 32; gb += 32;
  __syncthreads();

  int cur = 0;
  for (int k0 = 0; k0 < K; k0 += 32) {
    if (k0 + 32 < K) {
      int nx = (cur ^ 1) * 4096;
      gload_lds16(ga, lA0 + nx);
      gload_lds16(ga + 64 * K, lA1 + nx);
      gload_lds16(gb, lB0 + nx);
      gload_lds16(gb + 64 * K, lB1 + nx);
      ga += 32; gb += 32;
    }
    const u16* Ab = As + cur * 4096;
    const u16* Bb = Bs + cur * 4096;
    short8v af[4], bfv[4];
#pragma unroll
    for (int m = 0; m < 4; ++m)
      af[m] = *(const short8v*)(Ab + (wm + m * 16 + q) * 32 + g * 8);
#pragma unroll
    for (int n = 0; n < 4; ++n)
      bfv[n] = *(const short8v*)(Bb + (wn + n * 16 + q) * 32 + g * 8);
#pragma unroll
    for (int m = 0; m < 4; ++m)
#pragma unroll
      for (int n = 0; n < 4; ++n)
        acc[m][n] = mfma_bf16(af[m], bfv[n], acc[m][n]);
    __syncthreads();
    cur ^= 1;
  }

#pragma unroll
  for (int m = 0; m < 4; ++m) {
    int row0 = m0 + wm + m * 16 + g * 4;
#pragma unroll
    for (int n = 0; n < 4; ++n) {
      int col = n0 + wn + n * 16 + q;
      float bi = bias[col];
#pragma unroll
      for (int r2 = 0; r2 < 4; ++r2) {
        int row = row0 + r2;
        Cout[(size_t)row * EE + col] = acc[m][n][r2] + bi;
      }
    }
  }
}

extern "C" void kernel_launch(void* const* d_in, const int* in_sizes, int n_in,
                              void* d_out, int out_size, void* d_ws, size_t ws_size,
                              hipStream_t stream) {
  (void)in_sizes; (void)n_in; (void)out_size; (void)ws_size;
  const float* x    = (const float*)d_in[0];
  const float* Wqkv = (const float*)d_in[1];
  const float* bqkv = (const float*)d_in[2];
  const float* Wout = (const float*)d_in[3];
  const float* bout = (const float*)d_in[4];
  float* out = (float*)d_out;

  char* p = (char*)d_ws;
  u16* xb  = (u16*)p; p += (size_t)MT * EE * 2;           // 8 MB
  u16* wqT = (u16*)p; p += (size_t)NQ * EE * 2;           // 6 MB
  u16* woT = (u16*)p; p += (size_t)EE * EE * 2;           // 2 MB
  u16* Qs  = (u16*)p; p += (size_t)BB * HH * SS * DD * 2; // 8 MB
  u16* Ks  = (u16*)p; p += (size_t)BB * HH * SS * DD * 2; // 8 MB
  u16* Vt  = (u16*)p; p += (size_t)BB * HH * DD * SS * 2; // 8 MB
  u16* Ob  = (u16*)p; p += (size_t)MT * EE * 2;           // 8 MB

  cast_kernel<<<dim3((MT * EE / 4) / 256), dim3(256), 0, stream>>>(x, xb, MT * EE);
  transpose_kernel<<<dim3(NQ / 64, EE / 64), dim3(256), 0, stream>>>(Wqkv, wqT, EE, NQ);
  transpose_kernel<<<dim3(EE / 64, EE / 64), dim3(256), 0, stream>>>(Wout, woT, EE, EE);
  gemm_qkv_kernel<<<dim3(NQ / 128, MT / 128), dim3(256), 0, stream>>>(xb, wqT, bqkv, Qs, Ks, Vt);
  attn_kernel<<<dim3(1024), dim3(256), 0, stream>>>(Qs, Ks, Vt, Ob);
  gemm_out_kernel<<<dim3(EE / 128, MT / 128), dim3(256), 0, stream>>>(Ob, woT, bout, out);
}

// Round 14
// 121.074 us; speedup vs baseline: 1.0452x; 1.0452x over previous
//
#include <hip/hip_runtime.h>
#include <hip/hip_bf16.h>

#define BB 2
#define SS 2048
#define EE 1024
#define HH 16
#define DD 64
#define MT (BB*SS)     // 4096 tokens
#define NQ (3*EE)      // 3072

typedef unsigned short u16;
typedef __bf16 bf16t;
typedef bf16t bf16x8 __attribute__((ext_vector_type(8)));
typedef short short8v __attribute__((ext_vector_type(8)));
typedef float f32x4 __attribute__((ext_vector_type(4)));

#define AS1 __attribute__((address_space(1)))
#define AS3 __attribute__((address_space(3)))

__device__ __forceinline__ u16 f2b(float f) {
  unsigned u = __builtin_bit_cast(unsigned, f);
  u += 0x7FFF + ((u >> 16) & 1);   // RNE
  return (u16)(u >> 16);
}

__device__ __forceinline__ unsigned cvtpk(float lo, float hi) {
  unsigned r;
  asm("v_cvt_pk_bf16_f32 %0, %1, %2" : "=v"(r) : "v"(lo), "v"(hi));
  return r;
}

__device__ __forceinline__ void gload_lds16(const void* g, void* l) {
  __builtin_amdgcn_global_load_lds((const AS1 void*)(g), (AS3 void*)(l), 16, 0, 0);
}

__device__ __forceinline__ f32x4 mfma_bf16(short8v a, short8v b, f32x4 c) {
  return __builtin_amdgcn_mfma_f32_16x16x32_bf16(
      __builtin_bit_cast(bf16x8, a), __builtin_bit_cast(bf16x8, b), c, 0, 0, 0);
}

// scale folded into Q: 1/sqrt(64) * log2(e)
#define QSCALE 0.18033688f

// ---------------- prologue: cast x -> bf16 ----------------
__global__ void __launch_bounds__(256) cast_kernel(const float* __restrict__ in,
                                                   u16* __restrict__ out, int n) {
  int i = (blockIdx.x * 256 + threadIdx.x) * 4;
  if (i + 3 < n) {
    float4 v = *(const float4*)(in + i);
    ushort4 o;
    o.x = f2b(v.x); o.y = f2b(v.y); o.z = f2b(v.z); o.w = f2b(v.w);
    *(ushort4*)(out + i) = o;
  }
}

// W [K][N] f32 -> WT [N][K] bf16, 64x64 LDS tile (coalesced both sides)
__global__ void __launch_bounds__(256) transpose_kernel(const float* __restrict__ W,
                                                        u16* __restrict__ WT,
                                                        int K, int N) {
  __shared__ float t[64][65];
  int k0 = blockIdx.y * 64, n0 = blockIdx.x * 64;
  int r = threadIdx.x >> 4;          // 0..15
  int c4 = (threadIdx.x & 15) * 4;   // 0..60
#pragma unroll
  for (int i = 0; i < 4; ++i) {
    float4 v = *(const float4*)(W + (size_t)(k0 + r + i * 16) * N + n0 + c4);
    t[r + i * 16][c4 + 0] = v.x; t[r + i * 16][c4 + 1] = v.y;
    t[r + i * 16][c4 + 2] = v.z; t[r + i * 16][c4 + 3] = v.w;
  }
  __syncthreads();
#pragma unroll
  for (int i = 0; i < 4; ++i) {
    ushort4 o;
    o.x = f2b(t[c4 + 0][r + i * 16]); o.y = f2b(t[c4 + 1][r + i * 16]);
    o.z = f2b(t[c4 + 2][r + i * 16]); o.w = f2b(t[c4 + 3][r + i * 16]);
    *(ushort4*)(WT + (size_t)(n0 + r + i * 16) * K + k0 + c4) = o;
  }
}

// ---------------- QKV GEMM (2-phase dbuf): C = x @ Wqkv + b -> Q,K,Vt ------
__global__ void __launch_bounds__(256) gemm_qkv_kernel(
    const u16* __restrict__ A, const u16* __restrict__ BT,
    const float* __restrict__ bias,
    u16* __restrict__ Qs, u16* __restrict__ Ks, u16* __restrict__ Vt) {
  __shared__ u16 As[8192];   // 2 x 128x32
  __shared__ u16 Bs[8192];
  const int K = EE;
  int tid = threadIdx.x;
  int w = tid >> 6, lane = tid & 63;
  int g = lane >> 4, q = lane & 15;
  int m0 = blockIdx.y * 128, n0 = blockIdx.x * 128;
  int wm = (w >> 1) * 64, wn = (w & 1) * 64;

  f32x4 acc[4][4] = {};

  int r = tid >> 2;
  int kc = (tid & 3) * 8;
  const u16* ga = A + (size_t)(m0 + r) * K + kc;
  const u16* gb = BT + (size_t)(n0 + r) * K + kc;
  u16* lA0 = As + w * 512;
  u16* lA1 = As + 2048 + w * 512;
  u16* lB0 = Bs + w * 512;
  u16* lB1 = Bs + 2048 + w * 512;

  // prologue: stage k=0 into buf0
  gload_lds16(ga, lA0);
  gload_lds16(ga + 64 * K, lA1);
  gload_lds16(gb, lB0);
  gload_lds16(gb + 64 * K, lB1);
  ga += 32; gb += 32;
  __syncthreads();

  int cur = 0;
  for (int k0 = 0; k0 < K; k0 += 32) {
    if (k0 + 32 < K) {               // issue next-tile staging BEFORE compute
      int nx = (cur ^ 1) * 4096;
      gload_lds16(ga, lA0 + nx);
      gload_lds16(ga + 64 * K, lA1 + nx);
      gload_lds16(gb, lB0 + nx);
      gload_lds16(gb + 64 * K, lB1 + nx);
      ga += 32; gb += 32;
    }
    const u16* Ab = As + cur * 4096;
    const u16* Bb = Bs + cur * 4096;
    short8v af[4], bfv[4];
#pragma unroll
    for (int m = 0; m < 4; ++m)
      af[m] = *(const short8v*)(Ab + (wm + m * 16 + q) * 32 + g * 8);
#pragma unroll
    for (int n = 0; n < 4; ++n)
      bfv[n] = *(const short8v*)(Bb + (wn + n * 16 + q) * 32 + g * 8);
#pragma unroll
    for (int m = 0; m < 4; ++m)
#pragma unroll
      for (int n = 0; n < 4; ++n)
        acc[m][n] = mfma_bf16(af[m], bfv[n], acc[m][n]);
    __syncthreads();                 // drains staged loads; swap safe
    cur ^= 1;
  }

#pragma unroll
  for (int m = 0; m < 4; ++m) {
    int row0 = m0 + wm + m * 16 + g * 4;
#pragma unroll
    for (int n = 0; n < 4; ++n) {
      int col = n0 + wn + n * 16 + q;
      float bi = bias[col];
      int t = col >> 10;
      int h = (col >> 6) & 15;
      int d = col & 63;
      int b = row0 >> 11, s0 = row0 & 2047;
      size_t bh = (size_t)b * HH + h;
      if (t == 2) {
        ushort4 vv;
        vv.x = f2b(acc[m][n][0] + bi); vv.y = f2b(acc[m][n][1] + bi);
        vv.z = f2b(acc[m][n][2] + bi); vv.w = f2b(acc[m][n][3] + bi);
        *(ushort4*)&Vt[(bh * DD + d) * SS + s0] = vv;
      } else if (t == 0) {
#pragma unroll
        for (int r2 = 0; r2 < 4; ++r2)
          Qs[(bh * SS + s0 + r2) * DD + d] = f2b((acc[m][n][r2] + bi) * QSCALE);
      } else {
#pragma unroll
        for (int r2 = 0; r2 < 4; ++r2)
          Ks[(bh * SS + s0 + r2) * DD + d] = f2b(acc[m][n][r2] + bi);
      }
    }
  }
}

// ---------------- causal flash attention (8-wave, KVBLK=128 phases) ---------
// Round-12 structure (proven 54us) with phases of 128 kv (two 64-kv subtiles
// per barrier interval): barriers per block 2p+2 -> p+1; ONE shuffle-reduce +
// ONE defer-max check per 128 kv; two independent QK^T chains per phase give
// ILP inside the stall window. LDS 80KB (K dbuf 2x16K | V dbuf 2x16K | P
// 8x2K) -> exactly 2 blocks/CU. P buffer reused across subtiles. Rule-21
// swizzle throughout. Swapped S^T = mfma(K,Q); defer-max THR=8.
__global__ void __launch_bounds__(512) attn_kernel(
    const u16* __restrict__ Qg, const u16* __restrict__ Kg,
    const u16* __restrict__ Vg, u16* __restrict__ O) {
  __shared__ char lds[81920];   // K 2x16K @0 | V 2x16K @32768 | P 8x2K @65536
  const int tid = threadIdx.x;
  const int w = tid >> 6, lane = tid & 63;
  const int g = lane >> 4, q = lane & 15;
  const int bid = blockIdx.x;          // 0..511
  const int bh = bid & 31;             // bid%8 -> XCD; K/V L2-resident
  const int p = 15 - (bid >> 5);       // LPT: longest chunks dispatch first
  const int b = bh >> 4, h = bh & 15;
  char* Pw = lds + 65536 + w * 2048;
  const int qsw = (q & 7) << 4;        // swizzle for this lane's rows (row&7 == q&7)

  const char* Qp = (const char*)Qg + (size_t)bh * (SS * 128);
  const char* Kp = (const char*)Kg + (size_t)bh * (SS * 128);
  const char* Vp = (const char*)Vg + (size_t)bh * (SS * 128);  // [d][s]

  // K staging: 16KB/phase = 1024 16B-chunks; chunk e: row=e>>3, c16=e&7.
  // calls j=0,1 cover e = tid + j*512; LDS linear = e*16.
  const int kr0 = tid >> 3;
  const int kc0 = ((tid & 7) * 16) ^ ((kr0 & 7) << 4);
  const int kr1 = (tid + 512) >> 3;
  const int kc1 = ((tid & 7) * 16) ^ ((kr1 & 7) << 4);
  const char* Ksrc0 = Kp + kr0 * 128 + kc0;   // + ph*16384
  const char* Ksrc1 = Kp + kr1 * 128 + kc1;
  // V staging: 16KB/phase, tile [d=64][s=128] rows of 256B; chunk e: row=e>>4,
  // c16=e&15; within each 128B half apply inverse swizzle.
  const int vr0 = tid >> 4, vh0 = (tid & 15) >> 3;
  const int vc0 = vh0 * 128 + ((((tid & 7)) * 16) ^ ((vr0 & 7) << 4));
  const int vr1 = (tid + 512) >> 4, vh1 = ((tid + 512) & 15) >> 3;
  const int vc1 = vh1 * 128 + ((((tid & 7)) * 16) ^ ((vr1 & 7) << 4));
  const char* Vsrc0 = Vp + (size_t)vr0 * (SS * 2) + vc0;   // + ph*256
  const char* Vsrc1 = Vp + (size_t)vr1 * (SS * 2) + vc1;
  char* Kd0 = lds + w * 1024;            // + buf*16384
  char* Kd1 = lds + 8192 + w * 1024;
  char* Vd0 = lds + 32768 + w * 1024;
  char* Vd1 = lds + 32768 + 8192 + w * 1024;

  const int np = p + 1;                // phases of 128 kv
  const int qw = p * 128 + w * 16;     // wave's first q row

  short8v aq0 = *(const short8v*)(Qp + (size_t)(qw + q) * 128 + g * 16);
  short8v aq1 = *(const short8v*)(Qp + (size_t)(qw + q) * 128 + 64 + g * 16);

  f32x4 oacc[4] = {};                  // O^T[d=vfi*16+g*4+r2][qrow=qw+q]
  float mrun = -1e30f, lrun = 0.f;

  // prologue: stage phase 0
  gload_lds16(Ksrc0, Kd0);
  gload_lds16(Ksrc1, Kd1);
  gload_lds16(Vsrc0, Vd0);
  gload_lds16(Vsrc1, Vd1);
  __syncthreads();

  for (int ph = 0; ph < np; ++ph) {
    const int buf = ph & 1;
    if (ph + 1 < np) {                 // issue next-phase staging before compute
      size_t ko = (size_t)(ph + 1) * 16384;
      int vo = (ph + 1) * 256;
      int bo = (buf ^ 1) * 16384;
      gload_lds16(Ksrc0 + ko, Kd0 + bo);
      gload_lds16(Ksrc1 + ko, Kd1 + bo);
      gload_lds16(Vsrc0 + vo, Vd0 + bo);
      gload_lds16(Vsrc1 + vo, Vd1 + bo);
    }
    const int kv0 = ph << 7;
    const char* Kc = lds + buf * 16384;
    const char* Vc = lds + 32768 + buf * 16384;
    const bool actB = (kv0 + 64) <= qw + 15;   // wave-uniform

    // ---- S^T for subtile A (kv0..kv0+63) and B (kv0+64..kv0+127) ----
    f32x4 stA[4], stB[4];
    {
      short8v kf[4][2];
#pragma unroll
      for (int cc = 0; cc < 4; ++cc) {
        const char* kb = Kc + (cc * 16 + q) * 128;
        kf[cc][0] = *(const short8v*)(kb + ((g * 16) ^ qsw));
        kf[cc][1] = *(const short8v*)(kb + ((64 + g * 16) ^ qsw));
      }
#pragma unroll
      for (int cc = 0; cc < 4; ++cc) {
        f32x4 z = {};
        z = mfma_bf16(kf[cc][0], aq0, z);
        z = mfma_bf16(kf[cc][1], aq1, z);
        stA[cc] = z;
      }
    }
    if (actB) {
      short8v kf[4][2];
#pragma unroll
      for (int cc = 0; cc < 4; ++cc) {
        const char* kb = Kc + (64 + cc * 16 + q) * 128;
        kf[cc][0] = *(const short8v*)(kb + ((g * 16) ^ qsw));
        kf[cc][1] = *(const short8v*)(kb + ((64 + g * 16) ^ qsw));
      }
#pragma unroll
      for (int cc = 0; cc < 4; ++cc) {
        f32x4 z = {};
        z = mfma_bf16(kf[cc][0], aq0, z);
        z = mfma_bf16(kf[cc][1], aq1, z);
        stB[cc] = z;
      }
    }
    // ---- causal masks (diagonal only) ----
    {
      int row = qw + q;
      if (kv0 + 63 > row - 15) {       // subtile A may touch diagonal
#pragma unroll
        for (int cc = 0; cc < 4; ++cc) {
          int kvb = kv0 + cc * 16 + g * 4;
#pragma unroll
          for (int r2 = 0; r2 < 4; ++r2)
            if (kvb + r2 > row) stA[cc][r2] = -1e30f;
        }
      }
      if (actB && kv0 + 127 > row - 15) {
#pragma unroll
        for (int cc = 0; cc < 4; ++cc) {
          int kvb = kv0 + 64 + cc * 16 + g * 4;
#pragma unroll
          for (int r2 = 0; r2 < 4; ++r2)
            if (kvb + r2 > row) stB[cc][r2] = -1e30f;
        }
      }
    }
    // ---- ONE combined max + defer-max per 128 kv ----
    f32x4 t01, t23;
#pragma unroll
    for (int r2 = 0; r2 < 4; ++r2) {
      t01[r2] = fmaxf(stA[0][r2], stA[1][r2]);
      t23[r2] = fmaxf(stA[2][r2], stA[3][r2]);
    }
    if (actB) {
#pragma unroll
      for (int r2 = 0; r2 < 4; ++r2) {
        t01[r2] = fmaxf(t01[r2], fmaxf(stB[0][r2], stB[1][r2]));
        t23[r2] = fmaxf(t23[r2], fmaxf(stB[2][r2], stB[3][r2]));
      }
    }
    float mx = fmaxf(fmaxf(fmaxf(t01[0], t01[1]), fmaxf(t01[2], t01[3])),
                     fmaxf(fmaxf(t23[0], t23[1]), fmaxf(t23[2], t23[3])));
    mx = fmaxf(mx, __shfl_xor(mx, 16));
    mx = fmaxf(mx, __shfl_xor(mx, 32));
    if (!__all(mx - mrun <= 8.f)) {    // T13: rescale only on real growth
      float mnew = fmaxf(mrun, mx);
      float alpha = exp2f(mrun - mnew);
      mrun = mnew;
      lrun *= alpha;
#pragma unroll
      for (int vfi = 0; vfi < 4; ++vfi)
#pragma unroll
        for (int r2 = 0; r2 < 4; ++r2) oacc[vfi][r2] *= alpha;
    }
    // ---- subtile A: exp + pack + PV ----
    float sml;
    {
      f32x4 sum4 = {};
#pragma unroll
      for (int cc = 0; cc < 4; ++cc)
#pragma unroll
        for (int r2 = 0; r2 < 4; ++r2) {
          float pv = exp2f(stA[cc][r2] - mrun);
          stA[cc][r2] = pv;
          sum4[r2] += pv;
        }
      sml = (sum4[0] + sum4[1]) + (sum4[2] + sum4[3]);
      char* basep = Pw + q * 128;
#pragma unroll
      for (int cc = 0; cc < 4; ++cc) {
        unsigned p01 = cvtpk(stA[cc][0], stA[cc][1]);
        unsigned p23 = cvtpk(stA[cc][2], stA[cc][3]);
        *(unsigned*)(basep + ((32 * cc + 8 * g + 0) ^ qsw)) = p01;
        *(unsigned*)(basep + ((32 * cc + 8 * g + 4) ^ qsw)) = p23;
      }
      short8v pa0 = *(const short8v*)(basep + ((g * 16) ^ qsw));
      short8v pa1 = *(const short8v*)(basep + ((64 + g * 16) ^ qsw));
#pragma unroll
      for (int vfi = 0; vfi < 4; ++vfi) {
        const char* vb = Vc + (vfi * 16 + q) * 256;
        short8v v0 = *(const short8v*)(vb + ((g * 16) ^ qsw));
        short8v v1 = *(const short8v*)(vb + ((64 + g * 16) ^ qsw));
        oacc[vfi] = mfma_bf16(v0, pa0, oacc[vfi]);
        oacc[vfi] = mfma_bf16(v1, pa1, oacc[vfi]);
      }
    }
    // ---- subtile B: exp + pack + PV ----
    if (actB) {
      f32x4 sum4 = {};
#pragma unroll
      for (int cc = 0; cc < 4; ++cc)
#pragma unroll
        for (int r2 = 0; r2 < 4; ++r2) {
          float pv = exp2f(stB[cc][r2] - mrun);
          stB[cc][r2] = pv;
          sum4[r2] += pv;
        }
      sml += (sum4[0] + sum4[1]) + (sum4[2] + sum4[3]);
      char* basep = Pw + q * 128;
#pragma unroll
      for (int cc = 0; cc < 4; ++cc) {
        unsigned p01 = cvtpk(stB[cc][0], stB[cc][1]);
        unsigned p23 = cvtpk(stB[cc][2], stB[cc][3]);
        *(unsigned*)(basep + ((32 * cc + 8 * g + 0) ^ qsw)) = p01;
        *(unsigned*)(basep + ((32 * cc + 8 * g + 4) ^ qsw)) = p23;
      }
      short8v pa0 = *(const short8v*)(basep + ((g * 16) ^ qsw));
      short8v pa1 = *(const short8v*)(basep + ((64 + g * 16) ^ qsw));
#pragma unroll
      for (int vfi = 0; vfi < 4; ++vfi) {
        const char* vb = Vc + (vfi * 16 + q) * 256 + 128;
        short8v v0 = *(const short8v*)(vb + ((g * 16) ^ qsw));
        short8v v1 = *(const short8v*)(vb + ((64 + g * 16) ^ qsw));
        oacc[vfi] = mfma_bf16(v0, pa0, oacc[vfi]);
        oacc[vfi] = mfma_bf16(v1, pa1, oacc[vfi]);
      }
    }
    // ---- lrun update: one pair of shuffles per 128 kv ----
    sml += __shfl_xor(sml, 16);
    sml += __shfl_xor(sml, 32);
    lrun += sml;
    __syncthreads();                   // staged loads drained; buffers safe
  }

  // ---- epilogue ----
  {
    float inv = 1.0f / lrun;
    int row = qw + q;
    char* obase = (char*)O + (((size_t)b * SS + row) * EE + h * 64) * 2;
#pragma unroll
    for (int vfi = 0; vfi < 4; ++vfi) {
      uint2 o;
      o.x = cvtpk(oacc[vfi][0] * inv, oacc[vfi][1] * inv);
      o.y = cvtpk(oacc[vfi][2] * inv, oacc[vfi][3] * inv);
      *(uint2*)(obase + (vfi * 16 + g * 4) * 2) = o;
    }
  }
}

// ---------------- output projection GEMM (2-phase dbuf) ---------------------
__global__ void __launch_bounds__(256) gemm_out_kernel(
    const u16* __restrict__ A, const u16* __restrict__ BT,
    const float* __restrict__ bias, float* __restrict__ Cout) {
  __shared__ u16 As[8192];
  __shared__ u16 Bs[8192];
  const int K = EE;
  int tid = threadIdx.x;
  int w = tid >> 6, lane = tid & 63;
  int g = lane >> 4, q = lane & 15;
  int m0 = blockIdx.y * 128, n0 = blockIdx.x * 128;
  int wm = (w >> 1) * 64, wn = (w & 1) * 64;

  f32x4 acc[4][4] = {};

  int r = tid >> 2;
  int kc = (tid & 3) * 8;
  const u16* ga = A + (size_t)(m0 + r) * K + kc;
  const u16* gb = BT + (size_t)(n0 + r) * K + kc;
  u16* lA0 = As + w * 512;
  u16* lA1 = As + 2048 + w * 512;
  u16* lB0 = Bs + w * 512;
  u16* lB1 = Bs + 2048 + w * 512;

  gload_lds16(ga, lA0);
  gload_lds16(ga + 64 * K, lA1);
  gload_lds16(gb, lB0);
  gload_lds16(gb + 64 * K, lB1);
  ga += 32; gb += 32;
  __syncthreads();

  int cur = 0;
  for (int k0 = 0; k0 < K; k0 += 32) {
    if (k0 + 32 < K) {
      int nx = (cur ^ 1) * 4096;
      gload_lds16(ga, lA0 + nx);
      gload_lds16(ga + 64 * K, lA1 + nx);
      gload_lds16(gb, lB0 + nx);
      gload_lds16(gb + 64 * K, lB1 + nx);
      ga += 32; gb += 32;
    }
    const u16* Ab = As + cur * 4096;
    const u16* Bb = Bs + cur * 4096;
    short8v af[4], bfv[4];
#pragma unroll
    for (int m = 0; m < 4; ++m)
      af[m] = *(const short8v*)(Ab + (wm + m * 16 + q) * 32 + g * 8);
#pragma unroll
    for (int n = 0; n < 4; ++n)
      bfv[n] = *(const short8v*)(Bb + (wn + n * 16 + q) * 32 + g * 8);
#pragma unroll
    for (int m = 0; m < 4; ++m)
#pragma unroll
      for (int n = 0; n < 4; ++n)
        acc[m][n] = mfma_bf16(af[m], bfv[n], acc[m][n]);
    __syncthreads();
    cur ^= 1;
  }

#pragma unroll
  for (int m = 0; m < 4; ++m) {
    int row0 = m0 + wm + m * 16 + g * 4;
#pragma unroll
    for (int n = 0; n < 4; ++n) {
      int col = n0 + wn + n * 16 + q;
      float bi = bias[col];
#pragma unroll
      for (int r2 = 0; r2 < 4; ++r2) {
        int row = row0 + r2;
        Cout[(size_t)row * EE + col] = acc[m][n][r2] + bi;
      }
    }
  }
}

extern "C" void kernel_launch(void* const* d_in, const int* in_sizes, int n_in,
                              void* d_out, int out_size, void* d_ws, size_t ws_size,
                              hipStream_t stream) {
  (void)in_sizes; (void)n_in; (void)out_size; (void)ws_size;
  const float* x    = (const float*)d_in[0];
  const float* Wqkv = (const float*)d_in[1];
  const float* bqkv = (const float*)d_in[2];
  const float* Wout = (const float*)d_in[3];
  const float* bout = (const float*)d_in[4];
  float* out = (float*)d_out;

  char* p = (char*)d_ws;
  u16* xb  = (u16*)p; p += (size_t)MT * EE * 2;           // 8 MB
  u16* wqT = (u16*)p; p += (size_t)NQ * EE * 2;           // 6 MB
  u16* woT = (u16*)p; p += (size_t)EE * EE * 2;           // 2 MB
  u16* Qs  = (u16*)p; p += (size_t)BB * HH * SS * DD * 2; // 8 MB
  u16* Ks  = (u16*)p; p += (size_t)BB * HH * SS * DD * 2; // 8 MB
  u16* Vt  = (u16*)p; p += (size_t)BB * HH * DD * SS * 2; // 8 MB
  u16* Ob  = (u16*)p; p += (size_t)MT * EE * 2;           // 8 MB

  cast_kernel<<<dim3((MT * EE / 4) / 256), dim3(256), 0, stream>>>(x, xb, MT * EE);
  transpose_kernel<<<dim3(NQ / 64, EE / 64), dim3(256), 0, stream>>>(Wqkv, wqT, EE, NQ);
  transpose_kernel<<<dim3(EE / 64, EE / 64), dim3(256), 0, stream>>>(Wout, woT, EE, EE);
  gemm_qkv_kernel<<<dim3(NQ / 128, MT / 128), dim3(256), 0, stream>>>(xb, wqT, bqkv, Qs, Ks, Vt);
  attn_kernel<<<dim3(512), dim3(512), 0, stream>>>(Qs, Ks, Vt, Ob);
  gemm_out_kernel<<<dim3(EE / 128, MT / 128), dim3(256), 0, stream>>>(Ob, woT, bout, out);
}

// Round 15
// 120.342 us; speedup vs baseline: 1.0516x; 1.0061x over previous
//
#include <hip/hip_runtime.h>
#include <hip/hip_bf16.h>

#define BB 2
#define SS 2048
#define EE 1024
#define HH 16
#define DD 64
#define MT (BB*SS)     // 4096 tokens
#define NQ (3*EE)      // 3072

typedef unsigned short u16;
typedef __bf16 bf16t;
typedef bf16t bf16x8 __attribute__((ext_vector_type(8)));
typedef short short8v __attribute__((ext_vector_type(8)));
typedef float f32x4 __attribute__((ext_vector_type(4)));

#define AS1 __attribute__((address_space(1)))
#define AS3 __attribute__((address_space(3)))

__device__ __forceinline__ u16 f2b(float f) {
  unsigned u = __builtin_bit_cast(unsigned, f);
  u += 0x7FFF + ((u >> 16) & 1);   // RNE
  return (u16)(u >> 16);
}

__device__ __forceinline__ unsigned cvtpk(float lo, float hi) {
  unsigned r;
  asm("v_cvt_pk_bf16_f32 %0, %1, %2" : "=v"(r) : "v"(lo), "v"(hi));
  return r;
}

__device__ __forceinline__ void gload_lds16(const void* g, void* l) {
  __builtin_amdgcn_global_load_lds((const AS1 void*)(g), (AS3 void*)(l), 16, 0, 0);
}

__device__ __forceinline__ f32x4 mfma_bf16(short8v a, short8v b, f32x4 c) {
  return __builtin_amdgcn_mfma_f32_16x16x32_bf16(
      __builtin_bit_cast(bf16x8, a), __builtin_bit_cast(bf16x8, b), c, 0, 0, 0);
}

// scale folded into Q: 1/sqrt(64) * log2(e)
#define QSCALE 0.18033688f

// ---------------- prologue: cast x -> bf16 ----------------
__global__ void __launch_bounds__(256) cast_kernel(const float* __restrict__ in,
                                                   u16* __restrict__ out, int n) {
  int i = (blockIdx.x * 256 + threadIdx.x) * 4;
  if (i + 3 < n) {
    float4 v = *(const float4*)(in + i);
    ushort4 o;
    o.x = f2b(v.x); o.y = f2b(v.y); o.z = f2b(v.z); o.w = f2b(v.w);
    *(ushort4*)(out + i) = o;
  }
}

// W [K][N] f32 -> WT [N][K] bf16, 64x64 LDS tile (coalesced both sides)
__global__ void __launch_bounds__(256) transpose_kernel(const float* __restrict__ W,
                                                        u16* __restrict__ WT,
                                                        int K, int N) {
  __shared__ float t[64][65];
  int k0 = blockIdx.y * 64, n0 = blockIdx.x * 64;
  int r = threadIdx.x >> 4;          // 0..15
  int c4 = (threadIdx.x & 15) * 4;   // 0..60
#pragma unroll
  for (int i = 0; i < 4; ++i) {
    float4 v = *(const float4*)(W + (size_t)(k0 + r + i * 16) * N + n0 + c4);
    t[r + i * 16][c4 + 0] = v.x; t[r + i * 16][c4 + 1] = v.y;
    t[r + i * 16][c4 + 2] = v.z; t[r + i * 16][c4 + 3] = v.w;
  }
  __syncthreads();
#pragma unroll
  for (int i = 0; i < 4; ++i) {
    ushort4 o;
    o.x = f2b(t[c4 + 0][r + i * 16]); o.y = f2b(t[c4 + 1][r + i * 16]);
    o.z = f2b(t[c4 + 2][r + i * 16]); o.w = f2b(t[c4 + 3][r + i * 16]);
    *(ushort4*)(WT + (size_t)(n0 + r + i * 16) * K + k0 + c4) = o;
  }
}

// ---------------- QKV GEMM (2-phase dbuf): C = x @ Wqkv + b -> Q,K,Vt ------
__global__ void __launch_bounds__(256) gemm_qkv_kernel(
    const u16* __restrict__ A, const u16* __restrict__ BT,
    const float* __restrict__ bias,
    u16* __restrict__ Qs, u16* __restrict__ Ks, u16* __restrict__ Vt) {
  __shared__ u16 As[8192];   // 2 x 128x32
  __shared__ u16 Bs[8192];
  const int K = EE;
  int tid = threadIdx.x;
  int w = tid >> 6, lane = tid & 63;
  int g = lane >> 4, q = lane & 15;
  int m0 = blockIdx.y * 128, n0 = blockIdx.x * 128;
  int wm = (w >> 1) * 64, wn = (w & 1) * 64;

  f32x4 acc[4][4] = {};

  int r = tid >> 2;
  int kc = (tid & 3) * 8;
  const u16* ga = A + (size_t)(m0 + r) * K + kc;
  const u16* gb = BT + (size_t)(n0 + r) * K + kc;
  u16* lA0 = As + w * 512;
  u16* lA1 = As + 2048 + w * 512;
  u16* lB0 = Bs + w * 512;
  u16* lB1 = Bs + 2048 + w * 512;

  // prologue: stage k=0 into buf0
  gload_lds16(ga, lA0);
  gload_lds16(ga + 64 * K, lA1);
  gload_lds16(gb, lB0);
  gload_lds16(gb + 64 * K, lB1);
  ga += 32; gb += 32;
  __syncthreads();

  int cur = 0;
  for (int k0 = 0; k0 < K; k0 += 32) {
    if (k0 + 32 < K) {               // issue next-tile staging BEFORE compute
      int nx = (cur ^ 1) * 4096;
      gload_lds16(ga, lA0 + nx);
      gload_lds16(ga + 64 * K, lA1 + nx);
      gload_lds16(gb, lB0 + nx);
      gload_lds16(gb + 64 * K, lB1 + nx);
      ga += 32; gb += 32;
    }
    const u16* Ab = As + cur * 4096;
    const u16* Bb = Bs + cur * 4096;
    short8v af[4], bfv[4];
#pragma unroll
    for (int m = 0; m < 4; ++m)
      af[m] = *(const short8v*)(Ab + (wm + m * 16 + q) * 32 + g * 8);
#pragma unroll
    for (int n = 0; n < 4; ++n)
      bfv[n] = *(const short8v*)(Bb + (wn + n * 16 + q) * 32 + g * 8);
#pragma unroll
    for (int m = 0; m < 4; ++m)
#pragma unroll
      for (int n = 0; n < 4; ++n)
        acc[m][n] = mfma_bf16(af[m], bfv[n], acc[m][n]);
    __syncthreads();                 // drains staged loads; swap safe
    cur ^= 1;
  }

#pragma unroll
  for (int m = 0; m < 4; ++m) {
    int row0 = m0 + wm + m * 16 + g * 4;
#pragma unroll
    for (int n = 0; n < 4; ++n) {
      int col = n0 + wn + n * 16 + q;
      float bi = bias[col];
      int t = col >> 10;
      int h = (col >> 6) & 15;
      int d = col & 63;
      int b = row0 >> 11, s0 = row0 & 2047;
      size_t bh = (size_t)b * HH + h;
      if (t == 2) {
        ushort4 vv;
        vv.x = f2b(acc[m][n][0] + bi); vv.y = f2b(acc[m][n][1] + bi);
        vv.z = f2b(acc[m][n][2] + bi); vv.w = f2b(acc[m][n][3] + bi);
        *(ushort4*)&Vt[(bh * DD + d) * SS + s0] = vv;
      } else if (t == 0) {
#pragma unroll
        for (int r2 = 0; r2 < 4; ++r2)
          Qs[(bh * SS + s0 + r2) * DD + d] = f2b((acc[m][n][r2] + bi) * QSCALE);
      } else {
#pragma unroll
        for (int r2 = 0; r2 < 4; ++r2)
          Ks[(bh * SS + s0 + r2) * DD + d] = f2b(acc[m][n][r2] + bi);
      }
    }
  }
}

// ---------------- causal flash attention (8-wave, counted-vmcnt pipeline) ---
// Round-12 structure (KVBLK=64, rule-21 swizzle, swapped QK^T, defer-max)
// with T4: triple-buffered K/V LDS + raw s_barrier + COUNTED s_waitcnt
// vmcnt(2) -- next phase's 2 staged loads stay in flight ACROSS the barrier
// (never drained to 0 in the main loop; only the last phase waits vmcnt(0)).
// Phase s: wait own 2 loads; barrier; issue stage(s+2) into buf (s+2)%3
// (safe: that buf was last read at phase s-1, separated by this barrier);
// compute on buf s%3.
__global__ void __launch_bounds__(512) attn_kernel(
    const u16* __restrict__ Qg, const u16* __restrict__ Kg,
    const u16* __restrict__ Vg, u16* __restrict__ O) {
  __shared__ char lds[65536];   // K 3x8K @0 | V 3x8K @24576 | P 8x2K @49152
  const int tid = threadIdx.x;
  const int w = tid >> 6, lane = tid & 63;
  const int g = lane >> 4, q = lane & 15;
  const int bid = blockIdx.x;          // 0..511
  const int bh = bid & 31;             // bid%8 -> XCD; K/V L2-resident
  const int p = 15 - (bid >> 5);       // LPT: longest chunks dispatch first
  const int b = bh >> 4, h = bh & 15;
  char* Pw = lds + 49152 + w * 2048;
  const int qsw = (q & 7) << 4;        // swizzle for this lane's rows (row&7 == q&7)

  const char* Qp = (const char*)Qg + (size_t)bh * (SS * 128);
  const char* Kp = (const char*)Kg + (size_t)bh * (SS * 128);
  const char* Vp = (const char*)Vg + (size_t)bh * (SS * 128);  // [d][s]

  // staging map: thread -> (row 0..63, 16B chunk), inverse-swizzled source col
  const int srow = tid >> 3;
  const int ssw = ((tid & 7) * 16) ^ ((srow & 7) << 4);
  const char* Ksrc = Kp + srow * 128 + ssw;               // + s*8192
  const char* Vsrc = Vp + (size_t)srow * (SS * 2) + ssw;  // + s*128
  char* Kdst = lds + w * 1024;          // + buf*8192
  char* Vdst = lds + 24576 + w * 1024;

  const int nt = 2 * p + 2;            // >= 2 always
  const int qw = p * 128 + w * 16;     // wave's first q row

  short8v aq0 = *(const short8v*)(Qp + (size_t)(qw + q) * 128 + g * 16);
  short8v aq1 = *(const short8v*)(Qp + (size_t)(qw + q) * 128 + 64 + g * 16);

  f32x4 oacc[4] = {};                  // O^T[d=vfi*16+g*4+r2][qrow=qw+q]
  float mrun = -1e30f, lrun = 0.f;

  // prologue: stage phases 0 and 1 (2 loads each)
  gload_lds16(Ksrc, Kdst);
  gload_lds16(Vsrc, Vdst);
  gload_lds16(Ksrc + 8192, Kdst + 8192);
  gload_lds16(Vsrc + 128, Vdst + 8192);

  for (int s = 0; s < nt; ++s) {
    const int buf = s % 3;
    // counted wait: own phase's 2 loads done; next phase's 2 stay in flight
    if (s + 1 < nt) asm volatile("s_waitcnt vmcnt(2)" ::: "memory");
    else            asm volatile("s_waitcnt vmcnt(0)" ::: "memory");
    __builtin_amdgcn_s_barrier();
    if (s + 2 < nt) {                  // stage phase s+2 into buf (s+2)%3
      int nbuf = (s + 2) % 3;
      gload_lds16(Ksrc + (size_t)(s + 2) * 8192, Kdst + nbuf * 8192);
      gload_lds16(Vsrc + (s + 2) * 128, Vdst + nbuf * 8192);
    }
    const int kv0 = s << 6;
    if (kv0 <= qw + 15) {              // wave has unmasked work this tile
      const char* Kc = lds + buf * 8192;
      const char* Vc = lds + 24576 + buf * 8192;
      // ---- K fragments from swizzled LDS ----
      short8v kf[4][2];
#pragma unroll
      for (int cc = 0; cc < 4; ++cc) {
        const char* kb = Kc + (cc * 16 + q) * 128;
        kf[cc][0] = *(const short8v*)(kb + ((g * 16) ^ qsw));
        kf[cc][1] = *(const short8v*)(kb + ((64 + g * 16) ^ qsw));
      }
      // ---- S^T = K Q^T : lane holds S[qw+q][kv0 + cc*16 + g*4 + r2] ----
      f32x4 st[4];
#pragma unroll
      for (int cc = 0; cc < 4; ++cc) {
        f32x4 z = {};
        z = mfma_bf16(kf[cc][0], aq0, z);
        z = mfma_bf16(kf[cc][1], aq1, z);
        st[cc] = z;
      }
      // ---- V^T fragments from swizzled LDS ----
      short8v vf[4][2];
#pragma unroll
      for (int v = 0; v < 4; ++v) {
        const char* vb = Vc + (v * 16 + q) * 128;
        vf[v][0] = *(const short8v*)(vb + ((g * 16) ^ qsw));
        vf[v][1] = *(const short8v*)(vb + ((64 + g * 16) ^ qsw));
      }
      // ---- causal mask (diagonal tiles only) ----
      if (kv0 + 63 > qw) {
        int row = qw + q;
#pragma unroll
        for (int cc = 0; cc < 4; ++cc) {
          int kvb = kv0 + cc * 16 + g * 4;
#pragma unroll
          for (int r2 = 0; r2 < 4; ++r2)
            if (kvb + r2 > row) st[cc][r2] = -1e30f;
        }
      }
      // ---- online softmax (base-2; row lane-local, 2 shuffles) + defer-max --
      f32x4 t01, t23;
#pragma unroll
      for (int r2 = 0; r2 < 4; ++r2) {
        t01[r2] = fmaxf(st[0][r2], st[1][r2]);
        t23[r2] = fmaxf(st[2][r2], st[3][r2]);
      }
      float mx = fmaxf(fmaxf(fmaxf(t01[0], t01[1]), fmaxf(t01[2], t01[3])),
                       fmaxf(fmaxf(t23[0], t23[1]), fmaxf(t23[2], t23[3])));
      mx = fmaxf(mx, __shfl_xor(mx, 16));
      mx = fmaxf(mx, __shfl_xor(mx, 32));
      if (!__all(mx - mrun <= 8.f)) {  // T13: rescale only on real growth
        float mnew = fmaxf(mrun, mx);
        float alpha = exp2f(mrun - mnew);
        mrun = mnew;
        lrun *= alpha;
#pragma unroll
        for (int vfi = 0; vfi < 4; ++vfi)
#pragma unroll
          for (int r2 = 0; r2 < 4; ++r2) oacc[vfi][r2] *= alpha;
      }
      f32x4 sum4 = {};
#pragma unroll
      for (int cc = 0; cc < 4; ++cc)
#pragma unroll
        for (int r2 = 0; r2 < 4; ++r2) {
          float pv = exp2f(st[cc][r2] - mrun);
          st[cc][r2] = pv;
          sum4[r2] += pv;
        }
      float sm = (sum4[0] + sum4[1]) + (sum4[2] + sum4[3]);
      sm += __shfl_xor(sm, 16);
      sm += __shfl_xor(sm, 32);
      lrun += sm;
      // ---- P -> per-wave LDS packed bf16x2 (row = q, kv-contig) ----
      char* basep = Pw + q * 128;
#pragma unroll
      for (int cc = 0; cc < 4; ++cc) {
        unsigned p01 = cvtpk(st[cc][0], st[cc][1]);
        unsigned p23 = cvtpk(st[cc][2], st[cc][3]);
        *(unsigned*)(basep + ((32 * cc + 8 * g + 0) ^ qsw)) = p01;
        *(unsigned*)(basep + ((32 * cc + 8 * g + 4) ^ qsw)) = p23;
      }
      short8v pa0 = *(const short8v*)(basep + ((g * 16) ^ qsw));
      short8v pa1 = *(const short8v*)(basep + ((64 + g * 16) ^ qsw));
      // ---- O^T += V^T P ----
#pragma unroll
      for (int vfi = 0; vfi < 4; ++vfi) {
        oacc[vfi] = mfma_bf16(vf[vfi][0], pa0, oacc[vfi]);
        oacc[vfi] = mfma_bf16(vf[vfi][1], pa1, oacc[vfi]);
      }
    }
  }

  // ---- epilogue ----
  {
    float inv = 1.0f / lrun;
    int row = qw + q;
    char* obase = (char*)O + (((size_t)b * SS + row) * EE + h * 64) * 2;
#pragma unroll
    for (int vfi = 0; vfi < 4; ++vfi) {
      uint2 o;
      o.x = cvtpk(oacc[vfi][0] * inv, oacc[vfi][1] * inv);
      o.y = cvtpk(oacc[vfi][2] * inv, oacc[vfi][3] * inv);
      *(uint2*)(obase + (vfi * 16 + g * 4) * 2) = o;
    }
  }
}

// ---------------- output projection GEMM (2-phase dbuf) ---------------------
__global__ void __launch_bounds__(256) gemm_out_kernel(
    const u16* __restrict__ A, const u16* __restrict__ BT,
    const float* __restrict__ bias, float* __restrict__ Cout) {
  __shared__ u16 As[8192];
  __shared__ u16 Bs[8192];
  const int K = EE;
  int tid = threadIdx.x;
  int w = tid >> 6, lane = tid & 63;
  int g = lane >> 4, q = lane & 15;
  int m0 = blockIdx.y * 128, n0 = blockIdx.x * 128;
  int wm = (w >> 1) * 64, wn = (w & 1) * 64;

  f32x4 acc[4][4] = {};

  int r = tid >> 2;
  int kc = (tid & 3) * 8;
  const u16* ga = A + (size_t)(m0 + r) * K + kc;
  const u16* gb = BT + (size_t)(n0 + r) * K + kc;
  u16* lA0 = As + w * 512;
  u16* lA1 = As + 2048 + w * 512;
  u16* lB0 = Bs + w * 512;
  u16* lB1 = Bs + 2048 + w * 512;

  gload_lds16(ga, lA0);
  gload_lds16(ga + 64 * K, lA1);
  gload_lds16(gb, lB0);
  gload_lds16(gb + 64 * K, lB1);
  ga += 32; gb += 32;
  __syncthreads();

  int cur = 0;
  for (int k0 = 0; k0 < K; k0 += 32) {
    if (k0 + 32 < K) {
      int nx = (cur ^ 1) * 4096;
      gload_lds16(ga, lA0 + nx);
      gload_lds16(ga + 64 * K, lA1 + nx);
      gload_lds16(gb, lB0 + nx);
      gload_lds16(gb + 64 * K, lB1 + nx);
      ga += 32; gb += 32;
    }
    const u16* Ab = As + cur * 4096;
    const u16* Bb = Bs + cur * 4096;
    short8v af[4], bfv[4];
#pragma unroll
    for (int m = 0; m < 4; ++m)
      af[m] = *(const short8v*)(Ab + (wm + m * 16 + q) * 32 + g * 8);
#pragma unroll
    for (int n = 0; n < 4; ++n)
      bfv[n] = *(const short8v*)(Bb + (wn + n * 16 + q) * 32 + g * 8);
#pragma unroll
    for (int m = 0; m < 4; ++m)
#pragma unroll
      for (int n = 0; n < 4; ++n)
        acc[m][n] = mfma_bf16(af[m], bfv[n], acc[m][n]);
    __syncthreads();
    cur ^= 1;
  }

#pragma unroll
  for (int m = 0; m < 4; ++m) {
    int row0 = m0 + wm + m * 16 + g * 4;
#pragma unroll
    for (int n = 0; n < 4; ++n) {
      int col = n0 + wn + n * 16 + q;
      float bi = bias[col];
#pragma unroll
      for (int r2 = 0; r2 < 4; ++r2) {
        int row = row0 + r2;
        Cout[(size_t)row * EE + col] = acc[m][n][r2] + bi;
      }
    }
  }
}

extern "C" void kernel_launch(void* const* d_in, const int* in_sizes, int n_in,
                              void* d_out, int out_size, void* d_ws, size_t ws_size,
                              hipStream_t stream) {
  (void)in_sizes; (void)n_in; (void)out_size; (void)ws_size;
  const float* x    = (const float*)d_in[0];
  const float* Wqkv = (const float*)d_in[1];
  const float* bqkv = (const float*)d_in[2];
  const float* Wout = (const float*)d_in[3];
  const float* bout = (const float*)d_in[4];
  float* out = (float*)d_out;

  char* p = (char*)d_ws;
  u16* xb  = (u16*)p; p += (size_t)MT * EE * 2;           // 8 MB
  u16* wqT = (u16*)p; p += (size_t)NQ * EE * 2;           // 6 MB
  u16* woT = (u16*)p; p += (size_t)EE * EE * 2;           // 2 MB
  u16* Qs  = (u16*)p; p += (size_t)BB * HH * SS * DD * 2; // 8 MB
  u16* Ks  = (u16*)p; p += (size_t)BB * HH * SS * DD * 2; // 8 MB
  u16* Vt  = (u16*)p; p += (size_t)BB * HH * DD * SS * 2; // 8 MB
  u16* Ob  = (u16*)p; p += (size_t)MT * EE * 2;           // 8 MB

  cast_kernel<<<dim3((MT * EE / 4) / 256), dim3(256), 0, stream>>>(x, xb, MT * EE);
  transpose_kernel<<<dim3(NQ / 64, EE / 64), dim3(256), 0, stream>>>(Wqkv, wqT, EE, NQ);
  transpose_kernel<<<dim3(EE / 64, EE / 64), dim3(256), 0, stream>>>(Wout, woT, EE, EE);
  gemm_qkv_kernel<<<dim3(NQ / 128, MT / 128), dim3(256), 0, stream>>>(xb, wqT, bqkv, Qs, Ks, Vt);
  attn_kernel<<<dim3(512), dim3(512), 0, stream>>>(Qs, Ks, Vt, Ob);
  gemm_out_kernel<<<dim3(EE / 128, MT / 128), dim3(256), 0, stream>>>(Ob, woT, bout, out);
}